// Round 9
// baseline (327.268 us; speedup 1.0000x reference)
//
#include <hip/hip_runtime.h>

typedef unsigned int u32;
typedef unsigned short u16;
typedef _Float16 f16x2 __attribute__((ext_vector_type(2)));
typedef __bf16 bf16x8 __attribute__((ext_vector_type(8)));
typedef float f32x4 __attribute__((ext_vector_type(4)));

static __device__ __forceinline__ f16x2 bch(u32 u) { return __builtin_bit_cast(f16x2, u); }

// ---------------- ws layout (bytes) ----------------
// xp   (u32)  @ 0         : f16x2-packed x, [lvl][t*2+b][128 cpair][HW]; dead after repack
// A    (u16)  @ 11141120  : bf16 weights [lvl][o 256][k 2304], k=(g*9+p)*64+c
// corr (f32)  @ 15859712  : [lvl][b][K2][HW]; xq overlays after offset_kernel:
//             xq [lvl][b][g][hw][32 words], word bases {0,1048576,1310720,1376256}, ends @21430272
// offs (f32)  @ 27875840  : [lvl][b][72][HW], 783360 floats
// B fragments (chunked mode, 1024 rows x 2304 bf16 each):
//   g0 @ ws+0, g1 @ ws+4718592 (dead xp), g2 @ ws+21430272 (corr tail), g3 @ d_out (x0 slot)
// B full (big mode): BB @ ws+31009280, 10880 rows (needs ws >= 81144320)

__global__ __launch_bounds__(256) void pack_kernel(
    const float* __restrict__ x0, const float* __restrict__ x1,
    const float* __restrict__ x2, const float* __restrict__ x3,
    u32* __restrict__ xp)
{
  int i = blockIdx.x * 256 + threadIdx.x;
  const float* xs; int base, lg;
  if (i < 2097152)      { xs = x0; base = 0;       lg = 12; }
  else if (i < 2621440) { xs = x1; base = 2097152; lg = 10; }
  else if (i < 2752512) { xs = x2; base = 2621440; lg = 8;  }
  else if (i < 2785280) { xs = x3; base = 2752512; lg = 6;  }
  else return;
  int local = i - base;
  int HW = 1 << lg;
  int hw = local & (HW - 1);
  int plane = local >> lg;
  int tb = plane >> 7, cp = plane & 127;
  const float* s = xs + (size_t)(tb * 256 + cp * 2) * HW + hw;
  float f0 = s[0], f1 = s[HW];
  f16x2 h; h[0] = (_Float16)f0; h[1] = (_Float16)f1;
  xp[i] = __builtin_bit_cast(u32, h);
}

__global__ __launch_bounds__(256) void aconv_kernel(
    const float* __restrict__ w0, const float* __restrict__ w1,
    const float* __restrict__ w2, const float* __restrict__ w3,
    u16* __restrict__ A)
{
  int i = blockIdx.x * 256 + threadIdx.x;
  if (i >= 2359296) return;
  int lv = i / 589824;
  const float* w = (lv == 0) ? w0 : (lv == 1) ? w1 : (lv == 2) ? w2 : w3;
  int local = i - lv * 589824;
  int o = local / 2304;
  int k = local - o * 2304;
  int g = k / 576;
  int r = k - g * 576;
  int p = r >> 6;
  int c = r & 63;
  float v = w[(size_t)(o * 256 + g * 64 + c) * 9 + p];
  __bf16 bv = (__bf16)v;
  A[i] = __builtin_bit_cast(u16, bv);
}

// ---------------- fused correlation ----------------
// bx < 1280: L0 pair-reuse; bx in [1280,1440): L1 pair-reuse; bx >= 1440: L2/L3 small.
// Pair-reuse: tile 4x8 px; thread = slot(16: ty*4+pair) x kg(16). 5 qy-bands; lane owns
// pixel pair (txa, txa+s) and consecutive qx run -> nq+1 site loads feed 2*nq outputs.
// Hoisted staging + reg prefetch + dbuf LDS, one barrier per chunk.
__global__ __launch_bounds__(256) void corr_fused_kernel(const u32* __restrict__ xp, float* __restrict__ corr)
{
  __shared__ __align__(16) u32 x0w[4864];   // 2 x 2432 double buffer
  int t = threadIdx.x, bx = blockIdx.x;

  if (bx >= 1440) {
    int gw = ((bx - 1440) * 256 + t) >> 6;
    int lane = t & 63;
    int cs = lane >> 4, hwi = lane & 15;
    int obase = gw * 16;
    int K2, R, DISP, lgW, xpb, crb, rel;
    if (obase < 41472)      { K2 = 81; R = 9; DISP = 4; lgW = 4; xpb = 2621440; crb = 2959360; rel = obase; }
    else if (obase < 44672) { K2 = 25; R = 5; DISP = 2; lgW = 3; xpb = 2752512; crb = 3000832; rel = obase - 41472; }
    else return;
    int W = 1 << lgW, HW = W * W;
    int hw = (rel & (HW - 1)) + hwi;
    int rr = rel >> (2 * lgW);
    int k = rr % K2, b = rr / K2;
    int h = hw >> lgW, w = hw & (W - 1);
    int dy = k / R - DISP, dx = k % R - DISP;
    int h2 = h + dy, w2 = w + dx;
    float a = 0.f;
    if ((u32)h2 < (u32)W && (u32)w2 < (u32)W) {
      const u32* p1 = xp + xpb + (size_t)(2 + b) * 128 * HW + hw;
      const u32* p0 = xp + xpb + (size_t)b * 128 * HW + h2 * W + w2;
      int cp0 = cs * 32;
#pragma unroll 8
      for (int j = 0; j < 32; ++j) {
        int cp = cp0 + j;
        a = __builtin_amdgcn_fdot2(bch(p1[(size_t)cp * HW]), bch(p0[(size_t)cp * HW]), a, false);
      }
    }
    a += __shfl_xor(a, 16);
    a += __shfl_xor(a, 32);
    if (cs == 0)
      corr[crb + rel + hwi] = a * 0.00390625f;
    return;
  }

  int stride, lgW, xpb, crb, b, ks, ty0, tx0;
  if (bx < 1280) {
    stride = 2; lgW = 6; xpb = 0; crb = 0;
    ks = bx % 5; int r = bx / 5; b = r >> 7; int tile = r & 127;
    ty0 = (tile >> 3) * 4; tx0 = (tile & 7) * 8;
  } else {
    stride = 1; lgW = 5; xpb = 2097152; crb = 2367488;
    int l = bx - 1280; ks = l % 5; int r = l / 5; b = r >> 4; int tile = r & 15;
    ty0 = (tile >> 2) * 4; tx0 = (tile & 3) * 8;
  }
  int W = 1 << lgW, HW = W * W;
  int E = stride * 8;
  int WW = 8 + 2 * E;                  // 40 (L0), 24 (L1)
  int RS = WW * 6 + 2;                 // skewed row stride (breaks mod-32 aliasing)

  int slot = t & 15, kg = t >> 4;
  int ty = slot >> 2, pairid = slot & 3;
  int txa = (stride == 2) ? ((pairid & 1) + (pairid >> 1) * 4) : (pairid * 2);

  int qylo = (ks < 4) ? ks * 4 : 16;
  int dqy  = (ks < 4) ? 3 : 0;
  int nrows = 4 + stride * dqy;        // max 10 (L0), 7 (L1)
  int stcount = nrows * WW * 4;        // max 1600 -> 7 slots
  int nslot = (stcount + 255) >> 8;
  int rowlo = stride * qylo;

  int qy, qx0, nq;
  if (ks < 4) {
    qy = qylo + (kg & 3);
    int qxq = kg >> 2;
    qx0 = (qxq == 0) ? 0 : (qxq == 1) ? 5 : (qxq == 2) ? 9 : 13;
    nq  = (qxq == 0) ? 5 : 4;
  } else {
    qy = 16; qx0 = kg; nq = (kg == 15) ? 2 : 1;
  }

  float acc[2][5];
#pragma unroll
  for (int q = 0; q < 5; ++q) { acc[0][q] = 0.f; acc[1][q] = 0.f; }

  // staging geometry hoist
  int magic = (1 << 18) / WW + 1;
  u32 voff[7];
  u32 lvp[4] = {0u, 0u, 0u, 0u};
#pragma unroll
  for (int j = 0; j < 7; ++j) {
    u32 voj = 0, fl = 0;
    int idx = t + (j << 8);
    if (j < nslot && idx < stcount) {
      int s = idx >> 2, cw = idx & 3;
      int wy = (s * magic) >> 18;
      int wx = s - wy * WW;
      int gy = ty0 - E + rowlo + wy, gx = tx0 - E + wx;
      int la = wy * RS + wx * 6 + cw;
      if ((u32)gy < (u32)W && (u32)gx < (u32)W) {
        voj = (u32)(cw * HW + (gy << lgW) + gx);
        fl = 0x8000u | (u32)la;
      } else {
        x0w[la] = 0; x0w[2432 + la] = 0;   // OOB sites chunk-invariant: zero once
      }
    }
    voff[j] = voj;
    lvp[j >> 1] |= fl << ((j & 1) * 16);
  }

  const u32* xp0 = xp + xpb + (size_t)b * 128 * HW;
  const u32* xp1 = xp + xpb + (size_t)(2 + b) * 128 * HW;
  int pxa = ((ty0 + ty) << lgW) + tx0 + txa;

  u32 pf[7];
  u32 xpf[8];
  auto issue = [&](int ch2) {
    u32 cb = (u32)(ch2 * 4) * (u32)HW;
#pragma unroll
    for (int j = 0; j < 7; ++j) if (j < nslot) pf[j] = xp0[cb + voff[j]];
#pragma unroll
    for (int i = 0; i < 4; ++i) {
      xpf[i]     = xp1[cb + (u32)(i * HW) + (u32)pxa];
      xpf[4 + i] = xp1[cb + (u32)(i * HW) + (u32)(pxa + stride)];
    }
  };
  auto commit = [&](int bufb) {
#pragma unroll
    for (int j = 0; j < 7; ++j) {
      u32 w = lvp[j >> 1];
      u32 f = (j & 1) ? (w >> 16) : (w & 0xffffu);
      if (f & 0x8000u) x0w[bufb + (int)(f & 0x3fffu)] = pf[j];
    }
  };

  int sbq = (ty + stride * (qy - qylo)) * RS + txa * 6 + qx0 * 6 * stride;
  int step = 6 * stride;

  issue(0);
  for (int ch = 0; ch < 32; ++ch) {
    int bufb = (ch & 1) * 2432;
    commit(bufb);
    __syncthreads();
    f16x2 xa0 = bch(xpf[0]), xa1 = bch(xpf[1]), xa2 = bch(xpf[2]), xa3 = bch(xpf[3]);
    f16x2 xb0 = bch(xpf[4]), xb1 = bch(xpf[5]), xb2 = bch(xpf[6]), xb3 = bch(xpf[7]);
    if (ch < 31) issue(ch + 1);
    int a0 = bufb + sbq;
    uint2 c01 = *(const uint2*)(&x0w[a0]);
    uint2 c23 = *(const uint2*)(&x0w[a0 + 2]);
#pragma unroll
    for (int q = 0; q < 5; ++q) {
      if (q < nq) {
        int an = a0 + (q + 1) * step;
        uint2 n01 = *(const uint2*)(&x0w[an]);
        uint2 n23 = *(const uint2*)(&x0w[an + 2]);
        float s0 = acc[0][q];
        s0 = __builtin_amdgcn_fdot2(xa0, bch(c01.x), s0, false);
        s0 = __builtin_amdgcn_fdot2(xa1, bch(c01.y), s0, false);
        s0 = __builtin_amdgcn_fdot2(xa2, bch(c23.x), s0, false);
        s0 = __builtin_amdgcn_fdot2(xa3, bch(c23.y), s0, false);
        acc[0][q] = s0;
        float s1 = acc[1][q];
        s1 = __builtin_amdgcn_fdot2(xb0, bch(n01.x), s1, false);
        s1 = __builtin_amdgcn_fdot2(xb1, bch(n01.y), s1, false);
        s1 = __builtin_amdgcn_fdot2(xb2, bch(n23.x), s1, false);
        s1 = __builtin_amdgcn_fdot2(xb3, bch(n23.y), s1, false);
        acc[1][q] = s1;
        c01 = n01; c23 = n23;
      }
    }
  }
  int gya = ty0 + ty, gxa = tx0 + txa;
#pragma unroll
  for (int q = 0; q < 5; ++q) {
    if (q < nq) {
      int k = qy * 17 + qx0 + q;
      size_t base = crb + (size_t)(b * 289 + k) * HW + (gya << lgW) + gxa;
      corr[base]          = acc[0][q] * 0.00390625f;
      corr[base + stride] = acc[1][q] * 0.00390625f;
    }
  }
}

// ---------------- zero offs region (783360 floats) ----------------
__global__ __launch_bounds__(256) void zero_offs_kernel(float* __restrict__ offs)
{
  int i = blockIdx.x * 256 + threadIdx.x;
  if (i < 783360) offs[i] = 0.f;
}

// ---------------- offsets = w_off[72][K2] x corr[b][K2][HW], k-split x6, atomic combine ----
__global__ __launch_bounds__(256) void offset_kernel(
    const float* __restrict__ corr,
    const float* __restrict__ wo0, const float* __restrict__ wo1,
    const float* __restrict__ wo2, const float* __restrict__ wo3,
    float* __restrict__ offs)
{
  int t = threadIdx.x, bx = blockIdx.x;
  int kc = bx % 6;
  int unit = bx / 6;
  int og = unit & 3;
  int pb = unit >> 2;                 // 0..42

  int lgW, K2, crb, ofb, pbl;
  const float* wo;
  if (pb < 32)      { pbl = pb;      lgW = 6; K2 = 289; crb = 0;       ofb = 0;      wo = wo0; }
  else if (pb < 40) { pbl = pb - 32; lgW = 5; K2 = 289; crb = 2367488; ofb = 589824; wo = wo1; }
  else if (pb < 42) { pbl = pb - 40; lgW = 4; K2 = 81;  crb = 2959360; ofb = 737280; wo = wo2; }
  else              { pbl = 0;       lgW = 3; K2 = 25;  crb = 3000832; ofb = 774144; wo = wo3; }
  int HW = 1 << (2 * lgW);
  int pxg = pbl * 256 + t;
  if (lgW == 3 && t >= 128) return;   // L3 has only 128 px total
  int b = pxg >> (2 * lgW);
  int hw = pxg & (HW - 1);

  int kchunk = (K2 + 5) / 6;
  int klo = kc * kchunk;
  int khi = klo + kchunk; if (khi > K2) khi = K2;
  if (klo >= khi) return;

  const float* cr = corr + crb + (size_t)b * K2 * HW + hw;
  const float* wp = wo + (size_t)og * 18 * K2;   // block-uniform base
  float acc[18];
#pragma unroll
  for (int j = 0; j < 18; ++j) acc[j] = 0.f;
#pragma unroll 2
  for (int k = klo; k < khi; ++k) {
    float cv = cr[(size_t)k * HW];
#pragma unroll
    for (int j = 0; j < 18; ++j) acc[j] = fmaf(wp[(size_t)j * K2 + k], cv, acc[j]);
  }
  float* op = offs + ofb + ((size_t)b * 72 + og * 18) * HW + hw;
#pragma unroll
  for (int j = 0; j < 18; ++j) atomicAdd(&op[(size_t)j * HW], acc[j]);
}

__global__ __launch_bounds__(256) void repack_kernel(const u32* __restrict__ xp, u32* __restrict__ xq)
{
  __shared__ u32 lds[32 * 65];
  int t = threadIdx.x, bx = blockIdx.x;
  int local, lgW, xpb, xqb;
  if (bx < 512)      { local = bx;       lgW = 6; xpb = 0;       xqb = 0; }
  else if (bx < 640) { local = bx - 512; lgW = 5; xpb = 2097152; xqb = 1048576; }
  else if (bx < 672) { local = bx - 640; lgW = 4; xpb = 2621440; xqb = 1310720; }
  else               { local = bx - 672; lgW = 3; xpb = 2752512; xqb = 1376256; }
  int HW = 1 << (2 * lgW);
  int cpg_lg = 2 * lgW - 6;
  int hc = local & ((1 << cpg_lg) - 1);
  int g  = (local >> cpg_lg) & 3;
  int b  = local >> (cpg_lg + 2);
  int hw0 = hc * 64;
  int lane = t & 63, q = t >> 6;
  const u32* src = xp + xpb + (size_t)(2 + b) * 128 * HW + hw0 + lane;
#pragma unroll
  for (int j = 0; j < 8; ++j) {
    int p = q * 8 + j;
    lds[p * 65 + lane] = src[(size_t)(g * 32 + p) * HW];
  }
  __syncthreads();
  u32* dst = xq + xqb + ((size_t)((b * 4 + g) * HW + hw0)) * 32;
#pragma unroll
  for (int j = 0; j < 8; ++j) {
    int ow = j * 256 + t;
    int hwl = ow >> 5, w = ow & 31;
    dst[ow] = lds[w * 65 + hwl];
  }
}

// ---------------- bilinear sampler -> B[pix][2304] bf16 ----------------
__global__ __launch_bounds__(256) void sample_kernel(
    const u32* __restrict__ xq, const float* __restrict__ offs,
    u16* __restrict__ g0, u16* __restrict__ g1, u16* __restrict__ g2, u16* __restrict__ g3,
    u16* __restrict__ BB, int mode, int phase)
{
  int t = threadIdx.x, bx = blockIdx.x;
  int lvl, bsel, relblk;
  if (phase == 3) {
    if (bx < 2304)      { lvl = 0; bsel = 0; relblk = bx; }
    else if (bx < 4608) { lvl = 0; bsel = 1; relblk = bx - 2304; }
    else if (bx < 5760) { lvl = 1; bsel = 0; relblk = bx - 4608; }
    else if (bx < 6048) { lvl = 2; bsel = 0; relblk = bx - 5760; }
    else                { lvl = 3; bsel = 0; relblk = bx - 6048; }
  } else if (phase == 2) {
    if (bx < 1152)      { lvl = 1; bsel = 0; relblk = bx; }
    else if (bx < 1440) { lvl = 2; bsel = 0; relblk = bx - 1152; }
    else                { lvl = 3; bsel = 0; relblk = bx - 1440; }
  } else { lvl = 0; bsel = phase; relblk = bx; }

  int lgNPX = (lvl == 0) ? 12 : (lvl == 1) ? 11 : (lvl == 2) ? 9 : 7;
  int lgW   = (lvl == 0) ? 6  : (lvl == 1) ? 5  : (lvl == 2) ? 4 : 3;
  int xqb   = (lvl == 0) ? 0 : (lvl == 1) ? 1048576 : (lvl == 2) ? 1310720 : 1376256;
  int ofb   = (lvl == 0) ? 0 : (lvl == 1) ? 589824  : (lvl == 2) ? 737280  : 774144;
  int W = 1 << lgW, HW = W * W;

  int tid = relblk * 256 + t;
  int cq = tid & 3;
  int rest = tid >> 2;
  int px = rest & ((1 << lgNPX) - 1);
  int gp = rest >> lgNPX;

  int b, hw, cr, Rg;
  if (lvl == 0)      { b = bsel;     hw = px;        cr = px;       Rg = bsel * 4096 + px; }
  else if (lvl == 1) { b = px >> 10; hw = px & 1023; cr = px;       Rg = 8192 + px; }
  else if (lvl == 2) { b = px >> 8;  hw = px & 255;  cr = px;       Rg = 10240 + px; }
  else               { b = px >> 6;  hw = px & 63;   cr = 512 + px; Rg = 10752 + px; }

  u16* rowp;
  if (mode) rowp = BB + (size_t)Rg * 2304;
  else {
    u16* grp; int r;
    if (lvl >= 2) { grp = g2; r = cr; }
    else {
      int q = cr >> 10; r = cr & 1023;
      grp = (q == 0) ? g0 : (q == 1) ? g1 : (q == 2) ? g2 : g3;
    }
    rowp = grp + (size_t)r * 2304;
  }

  size_t ob = (size_t)ofb + ((size_t)b * 72 + gp * 2) * HW + hw;
  float ody = offs[ob], odx = offs[ob + HW];
  int g = gp / 9, p = gp - g * 9;
  int ky = p / 3, kx = p - ky * 3;
  int sh = hw >> lgW, sw = hw & (W - 1);
  float ys = (float)(sh + ky - 1) + ody;
  float xs = (float)(sw + kx - 1) + odx;
  float y0f = floorf(ys), x0f = floorf(xs);
  float wy = ys - y0f, wx = xs - x0f;
  int y0 = (int)y0f, x0 = (int)x0f, y1 = y0 + 1, x1 = x0 + 1;
  bool vy0 = (u32)y0 < (u32)W, vy1 = (u32)y1 < (u32)W;
  bool vx0 = (u32)x0 < (u32)W, vx1 = (u32)x1 < (u32)W;
  float w00 = (1.f - wy) * (1.f - wx), w01 = (1.f - wy) * wx;
  float w10 = wy * (1.f - wx), w11 = wy * wx;
  const u32* base = xq + xqb + ((size_t)(b * 4 + g) * HW) * 32 + cq * 8;
  const uint4 z = make_uint4(0, 0, 0, 0);
  uint4 a00 = z, c00 = z, a01 = z, c01 = z, a10 = z, c10 = z, a11 = z, c11 = z;
  if (vy0 && vx0) { const u32* p0 = base + (size_t)(y0 * W + x0) * 32; a00 = *(const uint4*)p0; c00 = *(const uint4*)(p0 + 4); }
  if (vy0 && vx1) { const u32* p0 = base + (size_t)(y0 * W + x1) * 32; a01 = *(const uint4*)p0; c01 = *(const uint4*)(p0 + 4); }
  if (vy1 && vx0) { const u32* p0 = base + (size_t)(y1 * W + x0) * 32; a10 = *(const uint4*)p0; c10 = *(const uint4*)(p0 + 4); }
  if (vy1 && vx1) { const u32* p0 = base + (size_t)(y1 * W + x1) * 32; a11 = *(const uint4*)p0; c11 = *(const uint4*)(p0 + 4); }
  bf16x8 r0, r1;
#pragma unroll
  for (int w = 0; w < 4; ++w) {
    f16x2 h00 = bch(((const u32*)&a00)[w]);
    f16x2 h01 = bch(((const u32*)&a01)[w]);
    f16x2 h10 = bch(((const u32*)&a10)[w]);
    f16x2 h11 = bch(((const u32*)&a11)[w]);
    float lo = w00 * (float)h00[0] + w01 * (float)h01[0] + w10 * (float)h10[0] + w11 * (float)h11[0];
    float hi = w00 * (float)h00[1] + w01 * (float)h01[1] + w10 * (float)h10[1] + w11 * (float)h11[1];
    r0[2 * w] = (__bf16)lo; r0[2 * w + 1] = (__bf16)hi;
  }
#pragma unroll
  for (int w = 0; w < 4; ++w) {
    f16x2 h00 = bch(((const u32*)&c00)[w]);
    f16x2 h01 = bch(((const u32*)&c01)[w]);
    f16x2 h10 = bch(((const u32*)&c10)[w]);
    f16x2 h11 = bch(((const u32*)&c11)[w]);
    float lo = w00 * (float)h00[0] + w01 * (float)h01[0] + w10 * (float)h10[0] + w11 * (float)h11[0];
    float hi = w00 * (float)h00[1] + w01 * (float)h01[1] + w10 * (float)h10[1] + w11 * (float)h11[1];
    r1[2 * w] = (__bf16)lo; r1[2 * w + 1] = (__bf16)hi;
  }
  u16* dst = rowp + gp * 64 + cq * 16;
  *(bf16x8*)dst = r0;
  *(bf16x8*)(dst + 8) = r1;
}

// ---------------- clean GEMM: C[256][pix] = A[256][2304] x B[pix][2304]^T + ReLU ----------------
__global__ __launch_bounds__(256) void gemm2_kernel(
    const u16* __restrict__ A,
    const u16* __restrict__ g0, const u16* __restrict__ g1,
    const u16* __restrict__ g2, const u16* __restrict__ g3,
    const u16* __restrict__ BB, int mode, int phase,
    float* __restrict__ out)
{
  __shared__ __align__(16) u16 Al[64 * 72];
  __shared__ __align__(16) u16 Bl[32 * 72];
  int t = threadIdx.x, bx = blockIdx.x;

  int lvl, bsel, local;
  if (phase == 3) {
    if (bx < 512)       { lvl = 0; bsel = 0; local = bx; }
    else if (bx < 1024) { lvl = 0; bsel = 1; local = bx - 512; }
    else {
      int r = bx - 1024;
      if (r < 256)      { lvl = 1; local = r; bsel = 0; }
      else if (r < 320) { lvl = 2; local = r - 256; bsel = 0; }
      else              { lvl = 3; local = r - 320; bsel = 0; }
    }
  } else if (phase == 2) {
    if (bx < 256)      { lvl = 1; local = bx; bsel = 0; }
    else if (bx < 320) { lvl = 2; local = bx - 256; bsel = 0; }
    else               { lvl = 3; local = bx - 320; bsel = 0; }
  } else { lvl = 0; bsel = phase; local = bx; }

  int mt = local & 3, nt = local >> 2;
  int px0 = nt * 32;
  int lgW, Ab, outb, b, hw0, cr0, Rg;
  if (lvl == 0)      { lgW = 6; Ab = 0;       outb = 2097152; b = bsel;      hw0 = px0;        cr0 = px0;       Rg = bsel * 4096 + px0; }
  else if (lvl == 1) { lgW = 5; Ab = 589824;  outb = 4718592; b = px0 >> 10; hw0 = px0 & 1023; cr0 = px0;       Rg = 8192 + px0; }
  else if (lvl == 2) { lgW = 4; Ab = 1179648; outb = 5373952; b = px0 >> 8;  hw0 = px0 & 255;  cr0 = px0;       Rg = 10240 + px0; }
  else               { lgW = 3; Ab = 1769472; outb = 5537792; b = px0 >> 6;  hw0 = px0 & 63;   cr0 = 512 + px0; Rg = 10752 + px0; }
  int HW = 1 << (2 * lgW);

  const u16* Bbase;
  if (mode) Bbase = BB + (size_t)Rg * 2304;
  else {
    const u16* grp; int r;
    if (lvl >= 2) { grp = g2; r = cr0; }
    else {
      int q = cr0 >> 10; r = cr0 & 1023;
      grp = (q == 0) ? g0 : (q == 1) ? g1 : (q == 2) ? g2 : g3;
    }
    Bbase = grp + (size_t)r * 2304;
  }

  int o0 = mt * 64;
  int l = t & 63, wv = t >> 6;
  int lr = l & 15, lk = l >> 4;
  int wvr = wv >> 1, wvc = wv & 1;

  int arow = t >> 2, ac4 = t & 3;
  int brow = t >> 3, bc8 = t & 7;
  const u16* Asrc = A + Ab + (size_t)(o0 + arow) * 2304 + ac4 * 16;
  const u16* Bsrc = Bbase + (size_t)brow * 2304 + bc8 * 8;

  f32x4 acc0 = {0, 0, 0, 0}, acc1 = {0, 0, 0, 0};
  uint4 ar0, ar1, br;
  auto issue = [&](int k0) {
    const uint4* as = (const uint4*)(Asrc + k0);
    ar0 = as[0]; ar1 = as[1];
    br = *(const uint4*)(Bsrc + k0);
  };
  auto commit = [&]() {
    *(uint4*)(&Al[arow * 72 + ac4 * 16]) = ar0;
    *(uint4*)(&Al[arow * 72 + ac4 * 16 + 8]) = ar1;
    *(uint4*)(&Bl[brow * 72 + bc8 * 8]) = br;
  };
  issue(0); commit();
  __syncthreads();
#pragma unroll 1
  for (int kt = 0; kt < 36; ++kt) {
    if (kt < 35) issue((kt + 1) * 64);
#pragma unroll
    for (int kk = 0; kk < 2; ++kk) {
      bf16x8 b0 = *(const bf16x8*)(&Bl[(wvc * 16 + lr) * 72 + kk * 32 + lk * 8]);
      bf16x8 a0 = *(const bf16x8*)(&Al[(wvr * 32 + lr) * 72 + kk * 32 + lk * 8]);
      bf16x8 a1 = *(const bf16x8*)(&Al[(wvr * 32 + 16 + lr) * 72 + kk * 32 + lk * 8]);
      acc0 = __builtin_amdgcn_mfma_f32_16x16x32_bf16(a0, b0, acc0, 0, 0, 0);
      acc1 = __builtin_amdgcn_mfma_f32_16x16x32_bf16(a1, b0, acc1, 0, 0, 0);
    }
    __syncthreads();
    if (kt < 35) { commit(); __syncthreads(); }
  }
  float* op = out + outb + (size_t)b * 256 * HW;
#pragma unroll
  for (int j = 0; j < 4; ++j) {
    int orow = o0 + wvr * 32 + lk * 4 + j;
    int col = hw0 + wvc * 16 + lr;
    op[(size_t)orow * HW + col]        = fmaxf(acc0[j], 0.f);
    op[(size_t)(orow + 16) * HW + col] = fmaxf(acc1[j], 0.f);
  }
}

extern "C" void kernel_launch(void* const* d_in, const int* in_sizes, int n_in,
                              void* d_out, int out_size, void* d_ws, size_t ws_size,
                              hipStream_t stream) {
  const float* x[4];
  const float* woff[4];
  const float* wad[4];
  for (int l = 0; l < 4; ++l) {
    x[l]    = (const float*)d_in[l];
    woff[l] = (const float*)d_in[4 + 2 * l];
    wad[l]  = (const float*)d_in[5 + 2 * l];
  }
  float* out = (float*)d_out;
  char* ws = (char*)d_ws;
  u32*   xp   = (u32*)(ws);
  u16*   A    = (u16*)(ws + 11141120);
  float* corr = (float*)(ws + 15859712);
  u32*   xq   = (u32*)(ws + 15859712);
  float* offs = (float*)(ws + 27875840);
  u16* g0 = (u16*)(ws + 0);
  u16* g1 = (u16*)(ws + 4718592);
  u16* g2 = (u16*)(ws + 21430272);
  u16* g3 = (u16*)d_out;
  u16* BB = (u16*)(ws + 31009280);
  int big = (ws_size >= (size_t)81144320) ? 1 : 0;

  zero_offs_kernel<<<3060, 256, 0, stream>>>(offs);
  pack_kernel<<<10880, 256, 0, stream>>>(x[0], x[1], x[2], x[3], xp);
  aconv_kernel<<<9216, 256, 0, stream>>>(wad[0], wad[1], wad[2], wad[3], A);
  corr_fused_kernel<<<2138, 256, 0, stream>>>(xp, corr);
  offset_kernel<<<1032, 256, 0, stream>>>(corr, woff[0], woff[1], woff[2], woff[3], offs);
  repack_kernel<<<680, 256, 0, stream>>>(xp, xq);

  if (big) {
    sample_kernel<<<6120, 256, 0, stream>>>(xq, offs, g0, g1, g2, g3, BB, 1, 3);
    gemm2_kernel<<<1360, 256, 0, stream>>>(A, g0, g1, g2, g3, BB, 1, 3, out);
  } else {
    sample_kernel<<<2304, 256, 0, stream>>>(xq, offs, g0, g1, g2, g3, BB, 0, 0);
    gemm2_kernel<<<512, 256, 0, stream>>>(A, g0, g1, g2, g3, BB, 0, 0, out);
    sample_kernel<<<2304, 256, 0, stream>>>(xq, offs, g0, g1, g2, g3, BB, 0, 1);
    gemm2_kernel<<<512, 256, 0, stream>>>(A, g0, g1, g2, g3, BB, 0, 1, out);
    sample_kernel<<<1512, 256, 0, stream>>>(xq, offs, g0, g1, g2, g3, BB, 0, 2);
    gemm2_kernel<<<336, 256, 0, stream>>>(A, g0, g1, g2, g3, BB, 0, 2, out);
  }

  hipMemcpyAsync(out + 0,       x[0], (size_t)2097152 * 4, hipMemcpyDeviceToDevice, stream);
  hipMemcpyAsync(out + 4194304, x[1], (size_t)524288 * 4,  hipMemcpyDeviceToDevice, stream);
  hipMemcpyAsync(out + 5242880, x[2], (size_t)131072 * 4,  hipMemcpyDeviceToDevice, stream);
  hipMemcpyAsync(out + 5505024, x[3], (size_t)32768 * 4,   hipMemcpyDeviceToDevice, stream);
}

// Round 10
// 327.151 us; speedup vs baseline: 1.0004x; 1.0004x over previous
//
#include <hip/hip_runtime.h>

typedef unsigned int u32;
typedef unsigned short u16;
typedef _Float16 f16x2 __attribute__((ext_vector_type(2)));
typedef __bf16 bf16x8 __attribute__((ext_vector_type(8)));
typedef float f32x4 __attribute__((ext_vector_type(4)));

static __device__ __forceinline__ f16x2 bch(u32 u) { return __builtin_bit_cast(f16x2, u); }

// ---------------- ws layout (bytes) ----------------
// xp   (u32)  @ 0         : f16x2-packed x, [lvl][t*2+b][128 cpair][HW]; dead after repack
// A    (u16)  @ 11141120  : bf16 weights [lvl][o 256][k 2304], k=(g*9+p)*64+c
// corr (f32)  @ 15859712  : [lvl][b][K2][HW]; xq overlays after offset_kernel:
//             xq [lvl][b][g][hw][32 words], word bases {0,1048576,1310720,1376256}, ends @21430272
// offs (f32)  @ 27875840  : [lvl][b][72][HW], 783360 floats
// B fragments (chunked mode, 1024 rows x 2304 bf16 each):
//   g0 @ ws+0, g1 @ ws+4718592 (dead xp), g2 @ ws+21430272 (corr tail), g3 @ d_out (x0 slot)
// B full (big mode): BB @ ws+31009280, 10880 rows (needs ws >= 81144320)

__global__ __launch_bounds__(256) void pack_kernel(
    const float* __restrict__ x0, const float* __restrict__ x1,
    const float* __restrict__ x2, const float* __restrict__ x3,
    u32* __restrict__ xp)
{
  int i = blockIdx.x * 256 + threadIdx.x;
  const float* xs; int base, lg;
  if (i < 2097152)      { xs = x0; base = 0;       lg = 12; }
  else if (i < 2621440) { xs = x1; base = 2097152; lg = 10; }
  else if (i < 2752512) { xs = x2; base = 2621440; lg = 8;  }
  else if (i < 2785280) { xs = x3; base = 2752512; lg = 6;  }
  else return;
  int local = i - base;
  int HW = 1 << lg;
  int hw = local & (HW - 1);
  int plane = local >> lg;
  int tb = plane >> 7, cp = plane & 127;
  const float* s = xs + (size_t)(tb * 256 + cp * 2) * HW + hw;
  float f0 = s[0], f1 = s[HW];
  f16x2 h; h[0] = (_Float16)f0; h[1] = (_Float16)f1;
  xp[i] = __builtin_bit_cast(u32, h);
}

__global__ __launch_bounds__(256) void aconv_kernel(
    const float* __restrict__ w0, const float* __restrict__ w1,
    const float* __restrict__ w2, const float* __restrict__ w3,
    u16* __restrict__ A)
{
  int i = blockIdx.x * 256 + threadIdx.x;
  if (i >= 2359296) return;
  int lv = i / 589824;
  const float* w = (lv == 0) ? w0 : (lv == 1) ? w1 : (lv == 2) ? w2 : w3;
  int local = i - lv * 589824;
  int o = local / 2304;
  int k = local - o * 2304;
  int g = k / 576;
  int r = k - g * 576;
  int p = r >> 6;
  int c = r & 63;
  float v = w[(size_t)(o * 256 + g * 64 + c) * 9 + p];
  __bf16 bv = (__bf16)v;
  A[i] = __builtin_bit_cast(u16, bv);
}

// ---------------- fused correlation ----------------
// bx < 1280: L0 pair-reuse; bx in [1280,1440): L1 pair-reuse; bx >= 1440: L2/L3 small.
// Pair-reuse: tile 4x8 px; thread = slot(16) x kg(16); lane owns pixel pair + consecutive
// qx run. Batched LDS reads (no predication in hot loop; store-guard only).
__global__ __launch_bounds__(256) void corr_fused_kernel(const u32* __restrict__ xp, float* __restrict__ corr)
{
  __shared__ __align__(16) u32 x0w[4864];   // 2 x 2432 double buffer
  int t = threadIdx.x, bx = blockIdx.x;

  if (bx >= 1440) {
    int gw = ((bx - 1440) * 256 + t) >> 6;
    int lane = t & 63;
    int cs = lane >> 4, hwi = lane & 15;
    int obase = gw * 16;
    int K2, R, DISP, lgW, xpb, crb, rel;
    if (obase < 41472)      { K2 = 81; R = 9; DISP = 4; lgW = 4; xpb = 2621440; crb = 2959360; rel = obase; }
    else if (obase < 44672) { K2 = 25; R = 5; DISP = 2; lgW = 3; xpb = 2752512; crb = 3000832; rel = obase - 41472; }
    else return;
    int W = 1 << lgW, HW = W * W;
    int hw = (rel & (HW - 1)) + hwi;
    int rr = rel >> (2 * lgW);
    int k = rr % K2, b = rr / K2;
    int h = hw >> lgW, w = hw & (W - 1);
    int dy = k / R - DISP, dx = k % R - DISP;
    int h2 = h + dy, w2 = w + dx;
    float a = 0.f;
    if ((u32)h2 < (u32)W && (u32)w2 < (u32)W) {
      const u32* p1 = xp + xpb + (size_t)(2 + b) * 128 * HW + hw;
      const u32* p0 = xp + xpb + (size_t)b * 128 * HW + h2 * W + w2;
      int cp0 = cs * 32;
#pragma unroll 8
      for (int j = 0; j < 32; ++j) {
        int cp = cp0 + j;
        a = __builtin_amdgcn_fdot2(bch(p1[(size_t)cp * HW]), bch(p0[(size_t)cp * HW]), a, false);
      }
    }
    a += __shfl_xor(a, 16);
    a += __shfl_xor(a, 32);
    if (cs == 0)
      corr[crb + rel + hwi] = a * 0.00390625f;
    return;
  }

  int stride, lgW, xpb, crb, b, ks, ty0, tx0;
  if (bx < 1280) {
    stride = 2; lgW = 6; xpb = 0; crb = 0;
    ks = bx % 5; int r = bx / 5; b = r >> 7; int tile = r & 127;
    ty0 = (tile >> 3) * 4; tx0 = (tile & 7) * 8;
  } else {
    stride = 1; lgW = 5; xpb = 2097152; crb = 2367488;
    int l = bx - 1280; ks = l % 5; int r = l / 5; b = r >> 4; int tile = r & 15;
    ty0 = (tile >> 2) * 4; tx0 = (tile & 3) * 8;
  }
  int W = 1 << lgW, HW = W * W;
  int E = stride * 8;
  int WW = 8 + 2 * E;                  // 40 (L0), 24 (L1)
  int RS = WW * 6 + 2;                 // skewed row stride

  int slot = t & 15, kg = t >> 4;
  int ty = slot >> 2, pairid = slot & 3;
  int txa = (stride == 2) ? ((pairid & 1) + (pairid >> 1) * 4) : (pairid * 2);

  int qylo = (ks < 4) ? ks * 4 : 16;
  int dqy  = (ks < 4) ? 3 : 0;
  int nrows = 4 + stride * dqy;        // max 10 (L0), 7 (L1)
  int stcount = nrows * WW * 4;
  int nslot = (stcount + 255) >> 8;
  int rowlo = stride * qylo;

  int qy, qx0, nq;
  if (ks < 4) {
    qy = qylo + (kg & 3);
    int qxq = kg >> 2;
    qx0 = (qxq == 0) ? 0 : (qxq == 1) ? 5 : (qxq == 2) ? 9 : 13;
    nq  = (qxq == 0) ? 5 : 4;
  } else {
    qy = 16; qx0 = kg; nq = (kg == 15) ? 2 : 1;
  }

  float acc[2][5];
#pragma unroll
  for (int q = 0; q < 5; ++q) { acc[0][q] = 0.f; acc[1][q] = 0.f; }

  // staging geometry hoist
  int magic = (1 << 18) / WW + 1;
  u32 voff[7];
  u32 lvp[4] = {0u, 0u, 0u, 0u};
#pragma unroll
  for (int j = 0; j < 7; ++j) {
    u32 voj = 0, fl = 0;
    int idx = t + (j << 8);
    if (j < nslot && idx < stcount) {
      int s = idx >> 2, cw = idx & 3;
      int wy = (s * magic) >> 18;
      int wx = s - wy * WW;
      int gy = ty0 - E + rowlo + wy, gx = tx0 - E + wx;
      int la = wy * RS + wx * 6 + cw;
      if ((u32)gy < (u32)W && (u32)gx < (u32)W) {
        voj = (u32)(cw * HW + (gy << lgW) + gx);
        fl = 0x8000u | (u32)la;
      } else {
        x0w[la] = 0; x0w[2432 + la] = 0;   // OOB sites chunk-invariant: zero once
      }
    }
    voff[j] = voj;
    lvp[j >> 1] |= fl << ((j & 1) * 16);
  }

  const u32* xp0 = xp + xpb + (size_t)b * 128 * HW;
  const u32* xp1 = xp + xpb + (size_t)(2 + b) * 128 * HW;
  int pxa = ((ty0 + ty) << lgW) + tx0 + txa;

  u32 pf[7];
  u32 xpf[8];
  auto issue = [&](int ch2) {
    u32 cb = (u32)(ch2 * 4) * (u32)HW;
#pragma unroll
    for (int j = 0; j < 7; ++j) if (j < nslot) pf[j] = xp0[cb + voff[j]];
#pragma unroll
    for (int i = 0; i < 4; ++i) {
      xpf[i]     = xp1[cb + (u32)(i * HW) + (u32)pxa];
      xpf[4 + i] = xp1[cb + (u32)(i * HW) + (u32)(pxa + stride)];
    }
  };
  auto commit = [&](int bufb) {
#pragma unroll
    for (int j = 0; j < 7; ++j) {
      u32 w = lvp[j >> 1];
      u32 f = (j & 1) ? (w >> 16) : (w & 0xffffu);
      if (f & 0x8000u) x0w[bufb + (int)(f & 0x3fffu)] = pf[j];
    }
  };

  int sbq = (ty + stride * (qy - qylo)) * RS + txa * 6 + qx0 * 6 * stride;
  int step = 6 * stride;

  issue(0);
  for (int ch = 0; ch < 32; ++ch) {
    int bufb = (ch & 1) * 2432;
    commit(bufb);
    __syncthreads();
    f16x2 xa0 = bch(xpf[0]), xa1 = bch(xpf[1]), xa2 = bch(xpf[2]), xa3 = bch(xpf[3]);
    f16x2 xb0 = bch(xpf[4]), xb1 = bch(xpf[5]), xb2 = bch(xpf[6]), xb3 = bch(xpf[7]);
    if (ch < 31) issue(ch + 1);
    int a0 = bufb + sbq;
    // batched, unconditional LDS reads (garbage beyond nq stays in-bounds, never stored)
    uint2 rd0[6], rd1[6];
#pragma unroll
    for (int q = 0; q < 6; ++q) {
      rd0[q] = *(const uint2*)(&x0w[a0 + q * step]);
      rd1[q] = *(const uint2*)(&x0w[a0 + q * step + 2]);
    }
#pragma unroll
    for (int q = 0; q < 5; ++q) {
      float s0 = acc[0][q];
      s0 = __builtin_amdgcn_fdot2(xa0, bch(rd0[q].x), s0, false);
      s0 = __builtin_amdgcn_fdot2(xa1, bch(rd0[q].y), s0, false);
      s0 = __builtin_amdgcn_fdot2(xa2, bch(rd1[q].x), s0, false);
      s0 = __builtin_amdgcn_fdot2(xa3, bch(rd1[q].y), s0, false);
      acc[0][q] = s0;
      float s1 = acc[1][q];
      s1 = __builtin_amdgcn_fdot2(xb0, bch(rd0[q + 1].x), s1, false);
      s1 = __builtin_amdgcn_fdot2(xb1, bch(rd0[q + 1].y), s1, false);
      s1 = __builtin_amdgcn_fdot2(xb2, bch(rd1[q + 1].x), s1, false);
      s1 = __builtin_amdgcn_fdot2(xb3, bch(rd1[q + 1].y), s1, false);
      acc[1][q] = s1;
    }
  }
  int gya = ty0 + ty, gxa = tx0 + txa;
#pragma unroll
  for (int q = 0; q < 5; ++q) {
    if (q < nq) {
      int k = qy * 17 + qx0 + q;
      size_t base = crb + (size_t)(b * 289 + k) * HW + (gya << lgW) + gxa;
      corr[base]          = acc[0][q] * 0.00390625f;
      corr[base + stride] = acc[1][q] * 0.00390625f;
    }
  }
}

// ---------------- zero offs region (783360 floats) ----------------
__global__ __launch_bounds__(256) void zero_offs_kernel(float* __restrict__ offs)
{
  int i = blockIdx.x * 256 + threadIdx.x;
  if (i < 783360) offs[i] = 0.f;
}

// ---------------- offsets = w_off[72][K2] x corr[b][K2][HW], k-split x6, atomic combine ----
__global__ __launch_bounds__(256) void offset_kernel(
    const float* __restrict__ corr,
    const float* __restrict__ wo0, const float* __restrict__ wo1,
    const float* __restrict__ wo2, const float* __restrict__ wo3,
    float* __restrict__ offs)
{
  int t = threadIdx.x, bx = blockIdx.x;
  int kc = bx % 6;
  int unit = bx / 6;
  int og = unit & 3;
  int pb = unit >> 2;                 // 0..42

  int lgW, K2, crb, ofb, pbl;
  const float* wo;
  if (pb < 32)      { pbl = pb;      lgW = 6; K2 = 289; crb = 0;       ofb = 0;      wo = wo0; }
  else if (pb < 40) { pbl = pb - 32; lgW = 5; K2 = 289; crb = 2367488; ofb = 589824; wo = wo1; }
  else if (pb < 42) { pbl = pb - 40; lgW = 4; K2 = 81;  crb = 2959360; ofb = 737280; wo = wo2; }
  else              { pbl = 0;       lgW = 3; K2 = 25;  crb = 3000832; ofb = 774144; wo = wo3; }
  int HW = 1 << (2 * lgW);
  int pxg = pbl * 256 + t;
  if (lgW == 3 && t >= 128) return;   // L3 has only 128 px total
  int b = pxg >> (2 * lgW);
  int hw = pxg & (HW - 1);

  int kchunk = (K2 + 5) / 6;
  int klo = kc * kchunk;
  int khi = klo + kchunk; if (khi > K2) khi = K2;
  if (klo >= khi) return;

  const float* cr = corr + crb + (size_t)b * K2 * HW + hw;
  const float* wp = wo + (size_t)og * 18 * K2;   // block-uniform base
  float acc[18];
#pragma unroll
  for (int j = 0; j < 18; ++j) acc[j] = 0.f;
#pragma unroll 2
  for (int k = klo; k < khi; ++k) {
    float cv = cr[(size_t)k * HW];
#pragma unroll
    for (int j = 0; j < 18; ++j) acc[j] = fmaf(wp[(size_t)j * K2 + k], cv, acc[j]);
  }
  float* op = offs + ofb + ((size_t)b * 72 + og * 18) * HW + hw;
#pragma unroll
  for (int j = 0; j < 18; ++j) atomicAdd(&op[(size_t)j * HW], acc[j]);
}

__global__ __launch_bounds__(256) void repack_kernel(const u32* __restrict__ xp, u32* __restrict__ xq)
{
  __shared__ u32 lds[32 * 65];
  int t = threadIdx.x, bx = blockIdx.x;
  int local, lgW, xpb, xqb;
  if (bx < 512)      { local = bx;       lgW = 6; xpb = 0;       xqb = 0; }
  else if (bx < 640) { local = bx - 512; lgW = 5; xpb = 2097152; xqb = 1048576; }
  else if (bx < 672) { local = bx - 640; lgW = 4; xpb = 2621440; xqb = 1310720; }
  else               { local = bx - 672; lgW = 3; xpb = 2752512; xqb = 1376256; }
  int HW = 1 << (2 * lgW);
  int cpg_lg = 2 * lgW - 6;
  int hc = local & ((1 << cpg_lg) - 1);
  int g  = (local >> cpg_lg) & 3;
  int b  = local >> (cpg_lg + 2);
  int hw0 = hc * 64;
  int lane = t & 63, q = t >> 6;
  const u32* src = xp + xpb + (size_t)(2 + b) * 128 * HW + hw0 + lane;
#pragma unroll
  for (int j = 0; j < 8; ++j) {
    int p = q * 8 + j;
    lds[p * 65 + lane] = src[(size_t)(g * 32 + p) * HW];
  }
  __syncthreads();
  u32* dst = xq + xqb + ((size_t)((b * 4 + g) * HW + hw0)) * 32;
#pragma unroll
  for (int j = 0; j < 8; ++j) {
    int ow = j * 256 + t;
    int hwl = ow >> 5, w = ow & 31;
    dst[ow] = lds[w * 65 + hwl];
  }
}

// ---------------- bilinear sampler -> B[pix][2304] bf16 ----------------
__global__ __launch_bounds__(256) void sample_kernel(
    const u32* __restrict__ xq, const float* __restrict__ offs,
    u16* __restrict__ g0, u16* __restrict__ g1, u16* __restrict__ g2, u16* __restrict__ g3,
    u16* __restrict__ BB, int mode, int phase)
{
  int t = threadIdx.x, bx = blockIdx.x;
  int lvl, bsel, relblk;
  if (phase == 3) {
    if (bx < 2304)      { lvl = 0; bsel = 0; relblk = bx; }
    else if (bx < 4608) { lvl = 0; bsel = 1; relblk = bx - 2304; }
    else if (bx < 5760) { lvl = 1; bsel = 0; relblk = bx - 4608; }
    else if (bx < 6048) { lvl = 2; bsel = 0; relblk = bx - 5760; }
    else                { lvl = 3; bsel = 0; relblk = bx - 6048; }
  } else if (phase == 2) {
    if (bx < 1152)      { lvl = 1; bsel = 0; relblk = bx; }
    else if (bx < 1440) { lvl = 2; bsel = 0; relblk = bx - 1152; }
    else                { lvl = 3; bsel = 0; relblk = bx - 1440; }
  } else { lvl = 0; bsel = phase; relblk = bx; }

  int lgNPX = (lvl == 0) ? 12 : (lvl == 1) ? 11 : (lvl == 2) ? 9 : 7;
  int lgW   = (lvl == 0) ? 6  : (lvl == 1) ? 5  : (lvl == 2) ? 4 : 3;
  int xqb   = (lvl == 0) ? 0 : (lvl == 1) ? 1048576 : (lvl == 2) ? 1310720 : 1376256;
  int ofb   = (lvl == 0) ? 0 : (lvl == 1) ? 589824  : (lvl == 2) ? 737280  : 774144;
  int W = 1 << lgW, HW = W * W;

  int tid = relblk * 256 + t;
  int cq = tid & 3;
  int rest = tid >> 2;
  int px = rest & ((1 << lgNPX) - 1);
  int gp = rest >> lgNPX;

  int b, hw, cr, Rg;
  if (lvl == 0)      { b = bsel;     hw = px;        cr = px;       Rg = bsel * 4096 + px; }
  else if (lvl == 1) { b = px >> 10; hw = px & 1023; cr = px;       Rg = 8192 + px; }
  else if (lvl == 2) { b = px >> 8;  hw = px & 255;  cr = px;       Rg = 10240 + px; }
  else               { b = px >> 6;  hw = px & 63;   cr = 512 + px; Rg = 10752 + px; }

  u16* rowp;
  if (mode) rowp = BB + (size_t)Rg * 2304;
  else {
    u16* grp; int r;
    if (lvl >= 2) { grp = g2; r = cr; }
    else {
      int q = cr >> 10; r = cr & 1023;
      grp = (q == 0) ? g0 : (q == 1) ? g1 : (q == 2) ? g2 : g3;
    }
    rowp = grp + (size_t)r * 2304;
  }

  size_t ob = (size_t)ofb + ((size_t)b * 72 + gp * 2) * HW + hw;
  float ody = offs[ob], odx = offs[ob + HW];
  int g = gp / 9, p = gp - g * 9;
  int ky = p / 3, kx = p - ky * 3;
  int sh = hw >> lgW, sw = hw & (W - 1);
  float ys = (float)(sh + ky - 1) + ody;
  float xs = (float)(sw + kx - 1) + odx;
  float y0f = floorf(ys), x0f = floorf(xs);
  float wy = ys - y0f, wx = xs - x0f;
  int y0 = (int)y0f, x0 = (int)x0f, y1 = y0 + 1, x1 = x0 + 1;
  bool vy0 = (u32)y0 < (u32)W, vy1 = (u32)y1 < (u32)W;
  bool vx0 = (u32)x0 < (u32)W, vx1 = (u32)x1 < (u32)W;
  float w00 = (1.f - wy) * (1.f - wx), w01 = (1.f - wy) * wx;
  float w10 = wy * (1.f - wx), w11 = wy * wx;
  const u32* base = xq + xqb + ((size_t)(b * 4 + g) * HW) * 32 + cq * 8;
  const uint4 z = make_uint4(0, 0, 0, 0);
  uint4 a00 = z, c00 = z, a01 = z, c01 = z, a10 = z, c10 = z, a11 = z, c11 = z;
  if (vy0 && vx0) { const u32* p0 = base + (size_t)(y0 * W + x0) * 32; a00 = *(const uint4*)p0; c00 = *(const uint4*)(p0 + 4); }
  if (vy0 && vx1) { const u32* p0 = base + (size_t)(y0 * W + x1) * 32; a01 = *(const uint4*)p0; c01 = *(const uint4*)(p0 + 4); }
  if (vy1 && vx0) { const u32* p0 = base + (size_t)(y1 * W + x0) * 32; a10 = *(const uint4*)p0; c10 = *(const uint4*)(p0 + 4); }
  if (vy1 && vx1) { const u32* p0 = base + (size_t)(y1 * W + x1) * 32; a11 = *(const uint4*)p0; c11 = *(const uint4*)(p0 + 4); }
  bf16x8 r0, r1;
#pragma unroll
  for (int w = 0; w < 4; ++w) {
    f16x2 h00 = bch(((const u32*)&a00)[w]);
    f16x2 h01 = bch(((const u32*)&a01)[w]);
    f16x2 h10 = bch(((const u32*)&a10)[w]);
    f16x2 h11 = bch(((const u32*)&a11)[w]);
    float lo = w00 * (float)h00[0] + w01 * (float)h01[0] + w10 * (float)h10[0] + w11 * (float)h11[0];
    float hi = w00 * (float)h00[1] + w01 * (float)h01[1] + w10 * (float)h10[1] + w11 * (float)h11[1];
    r0[2 * w] = (__bf16)lo; r0[2 * w + 1] = (__bf16)hi;
  }
#pragma unroll
  for (int w = 0; w < 4; ++w) {
    f16x2 h00 = bch(((const u32*)&c00)[w]);
    f16x2 h01 = bch(((const u32*)&c01)[w]);
    f16x2 h10 = bch(((const u32*)&c10)[w]);
    f16x2 h11 = bch(((const u32*)&c11)[w]);
    float lo = w00 * (float)h00[0] + w01 * (float)h01[0] + w10 * (float)h10[0] + w11 * (float)h11[0];
    float hi = w00 * (float)h00[1] + w01 * (float)h01[1] + w10 * (float)h10[1] + w11 * (float)h11[1];
    r1[2 * w] = (__bf16)lo; r1[2 * w + 1] = (__bf16)hi;
  }
  u16* dst = rowp + gp * 64 + cq * 16;
  *(bf16x8*)dst = r0;
  *(bf16x8*)(dst + 8) = r1;
}

// ---------------- clean GEMM: C[256][pix] = A[256][2304] x B[pix][2304]^T + ReLU ----------------
__global__ __launch_bounds__(256) void gemm2_kernel(
    const u16* __restrict__ A,
    const u16* __restrict__ g0, const u16* __restrict__ g1,
    const u16* __restrict__ g2, const u16* __restrict__ g3,
    const u16* __restrict__ BB, int mode, int phase,
    float* __restrict__ out)
{
  __shared__ __align__(16) u16 Al[64 * 72];
  __shared__ __align__(16) u16 Bl[32 * 72];
  int t = threadIdx.x, bx = blockIdx.x;

  int lvl, bsel, local;
  if (phase == 3) {
    if (bx < 512)       { lvl = 0; bsel = 0; local = bx; }
    else if (bx < 1024) { lvl = 0; bsel = 1; local = bx - 512; }
    else {
      int r = bx - 1024;
      if (r < 256)      { lvl = 1; local = r; bsel = 0; }
      else if (r < 320) { lvl = 2; local = r - 256; bsel = 0; }
      else              { lvl = 3; local = r - 320; bsel = 0; }
    }
  } else if (phase == 2) {
    if (bx < 256)      { lvl = 1; local = bx; bsel = 0; }
    else if (bx < 320) { lvl = 2; local = bx - 256; bsel = 0; }
    else               { lvl = 3; local = bx - 320; bsel = 0; }
  } else { lvl = 0; bsel = phase; local = bx; }

  int mt = local & 3, nt = local >> 2;
  int px0 = nt * 32;
  int lgW, Ab, outb, b, hw0, cr0, Rg;
  if (lvl == 0)      { lgW = 6; Ab = 0;       outb = 2097152; b = bsel;      hw0 = px0;        cr0 = px0;       Rg = bsel * 4096 + px0; }
  else if (lvl == 1) { lgW = 5; Ab = 589824;  outb = 4718592; b = px0 >> 10; hw0 = px0 & 1023; cr0 = px0;       Rg = 8192 + px0; }
  else if (lvl == 2) { lgW = 4; Ab = 1179648; outb = 5373952; b = px0 >> 8;  hw0 = px0 & 255;  cr0 = px0;       Rg = 10240 + px0; }
  else               { lgW = 3; Ab = 1769472; outb = 5537792; b = px0 >> 6;  hw0 = px0 & 63;   cr0 = 512 + px0; Rg = 10752 + px0; }
  int HW = 1 << (2 * lgW);

  const u16* Bbase;
  if (mode) Bbase = BB + (size_t)Rg * 2304;
  else {
    const u16* grp; int r;
    if (lvl >= 2) { grp = g2; r = cr0; }
    else {
      int q = cr0 >> 10; r = cr0 & 1023;
      grp = (q == 0) ? g0 : (q == 1) ? g1 : (q == 2) ? g2 : g3;
    }
    Bbase = grp + (size_t)r * 2304;
  }

  int o0 = mt * 64;
  int l = t & 63, wv = t >> 6;
  int lr = l & 15, lk = l >> 4;
  int wvr = wv >> 1, wvc = wv & 1;

  int arow = t >> 2, ac4 = t & 3;
  int brow = t >> 3, bc8 = t & 7;
  const u16* Asrc = A + Ab + (size_t)(o0 + arow) * 2304 + ac4 * 16;
  const u16* Bsrc = Bbase + (size_t)brow * 2304 + bc8 * 8;

  f32x4 acc0 = {0, 0, 0, 0}, acc1 = {0, 0, 0, 0};
  uint4 ar0, ar1, br;
  auto issue = [&](int k0) {
    const uint4* as = (const uint4*)(Asrc + k0);
    ar0 = as[0]; ar1 = as[1];
    br = *(const uint4*)(Bsrc + k0);
  };
  auto commit = [&]() {
    *(uint4*)(&Al[arow * 72 + ac4 * 16]) = ar0;
    *(uint4*)(&Al[arow * 72 + ac4 * 16 + 8]) = ar1;
    *(uint4*)(&Bl[brow * 72 + bc8 * 8]) = br;
  };
  issue(0); commit();
  __syncthreads();
#pragma unroll 1
  for (int kt = 0; kt < 36; ++kt) {
    if (kt < 35) issue((kt + 1) * 64);
#pragma unroll
    for (int kk = 0; kk < 2; ++kk) {
      bf16x8 b0 = *(const bf16x8*)(&Bl[(wvc * 16 + lr) * 72 + kk * 32 + lk * 8]);
      bf16x8 a0 = *(const bf16x8*)(&Al[(wvr * 32 + lr) * 72 + kk * 32 + lk * 8]);
      bf16x8 a1 = *(const bf16x8*)(&Al[(wvr * 32 + 16 + lr) * 72 + kk * 32 + lk * 8]);
      acc0 = __builtin_amdgcn_mfma_f32_16x16x32_bf16(a0, b0, acc0, 0, 0, 0);
      acc1 = __builtin_amdgcn_mfma_f32_16x16x32_bf16(a1, b0, acc1, 0, 0, 0);
    }
    __syncthreads();
    if (kt < 35) { commit(); __syncthreads(); }
  }
  float* op = out + outb + (size_t)b * 256 * HW;
#pragma unroll
  for (int j = 0; j < 4; ++j) {
    int orow = o0 + wvr * 32 + lk * 4 + j;
    int col = hw0 + wvc * 16 + lr;
    op[(size_t)orow * HW + col]        = fmaxf(acc0[j], 0.f);
    op[(size_t)(orow + 16) * HW + col] = fmaxf(acc1[j], 0.f);
  }
}

extern "C" void kernel_launch(void* const* d_in, const int* in_sizes, int n_in,
                              void* d_out, int out_size, void* d_ws, size_t ws_size,
                              hipStream_t stream) {
  const float* x[4];
  const float* woff[4];
  const float* wad[4];
  for (int l = 0; l < 4; ++l) {
    x[l]    = (const float*)d_in[l];
    woff[l] = (const float*)d_in[4 + 2 * l];
    wad[l]  = (const float*)d_in[5 + 2 * l];
  }
  float* out = (float*)d_out;
  char* ws = (char*)d_ws;
  u32*   xp   = (u32*)(ws);
  u16*   A    = (u16*)(ws + 11141120);
  float* corr = (float*)(ws + 15859712);
  u32*   xq   = (u32*)(ws + 15859712);
  float* offs = (float*)(ws + 27875840);
  u16* g0 = (u16*)(ws + 0);
  u16* g1 = (u16*)(ws + 4718592);
  u16* g2 = (u16*)(ws + 21430272);
  u16* g3 = (u16*)d_out;
  u16* BB = (u16*)(ws + 31009280);
  int big = (ws_size >= (size_t)81144320) ? 1 : 0;

  zero_offs_kernel<<<3060, 256, 0, stream>>>(offs);
  pack_kernel<<<10880, 256, 0, stream>>>(x[0], x[1], x[2], x[3], xp);
  aconv_kernel<<<9216, 256, 0, stream>>>(wad[0], wad[1], wad[2], wad[3], A);
  corr_fused_kernel<<<2138, 256, 0, stream>>>(xp, corr);
  offset_kernel<<<1032, 256, 0, stream>>>(corr, woff[0], woff[1], woff[2], woff[3], offs);
  repack_kernel<<<680, 256, 0, stream>>>(xp, xq);

  if (big) {
    sample_kernel<<<6120, 256, 0, stream>>>(xq, offs, g0, g1, g2, g3, BB, 1, 3);
    gemm2_kernel<<<1360, 256, 0, stream>>>(A, g0, g1, g2, g3, BB, 1, 3, out);
  } else {
    sample_kernel<<<2304, 256, 0, stream>>>(xq, offs, g0, g1, g2, g3, BB, 0, 0);
    gemm2_kernel<<<512, 256, 0, stream>>>(A, g0, g1, g2, g3, BB, 0, 0, out);
    sample_kernel<<<2304, 256, 0, stream>>>(xq, offs, g0, g1, g2, g3, BB, 0, 1);
    gemm2_kernel<<<512, 256, 0, stream>>>(A, g0, g1, g2, g3, BB, 0, 1, out);
    sample_kernel<<<1512, 256, 0, stream>>>(xq, offs, g0, g1, g2, g3, BB, 0, 2);
    gemm2_kernel<<<336, 256, 0, stream>>>(A, g0, g1, g2, g3, BB, 0, 2, out);
  }

  hipMemcpyAsync(out + 0,       x[0], (size_t)2097152 * 4, hipMemcpyDeviceToDevice, stream);
  hipMemcpyAsync(out + 4194304, x[1], (size_t)524288 * 4,  hipMemcpyDeviceToDevice, stream);
  hipMemcpyAsync(out + 5242880, x[2], (size_t)131072 * 4,  hipMemcpyDeviceToDevice, stream);
  hipMemcpyAsync(out + 5505024, x[3], (size_t)32768 * 4,   hipMemcpyDeviceToDevice, stream);
}

// Round 11
// 183.176 us; speedup vs baseline: 1.7866x; 1.7860x over previous
//
#include <hip/hip_runtime.h>

typedef unsigned int u32;
typedef unsigned short u16;
typedef _Float16 f16x2 __attribute__((ext_vector_type(2)));
typedef __bf16 bf16x8 __attribute__((ext_vector_type(8)));
typedef float f32x4 __attribute__((ext_vector_type(4)));

static __device__ __forceinline__ f16x2 bch(u32 u) { return __builtin_bit_cast(f16x2, u); }

// ---------------- ws layout (bytes) ----------------
// xp   (u32)  @ 0         : f16x2-packed x, [lvl][t*2+b][128 cpair][HW]; dead after repack
// A    (u16)  @ 11141120  : bf16 weights [lvl][o 256][k 2304], k=(g*9+p)*64+c
// corr (f32)  @ 15859712  : [lvl][b][K2][HW]; xq overlays after offset_kernel:
//             xq [lvl][b][g][hw][32 words], word bases {0,1048576,1310720,1376256}, ends @21430272
// offs (f32)  @ 27875840  : [lvl][b][72][HW], 783360 floats
// B fragments (chunked mode, 1024 rows x 2304 bf16 each):
//   g0 @ ws+0, g1 @ ws+4718592 (dead xp), g2 @ ws+21430272 (corr tail), g3 @ d_out (x0 slot)
// B full (big mode): BB @ ws+31009280, 10880 rows (needs ws >= 81144320)

// ---------------- merged preamble: zero offs + pack x + convert w_adapt ----------------
__global__ __launch_bounds__(256) void prep_kernel(
    const float* __restrict__ x0, const float* __restrict__ x1,
    const float* __restrict__ x2, const float* __restrict__ x3,
    const float* __restrict__ w0, const float* __restrict__ w1,
    const float* __restrict__ w2, const float* __restrict__ w3,
    u32* __restrict__ xp, u16* __restrict__ A, float* __restrict__ offs)
{
  int bx = blockIdx.x, t = threadIdx.x;
  if (bx < 3060) {
    int i = bx * 256 + t;
    if (i < 783360) offs[i] = 0.f;
    return;
  }
  if (bx < 13940) {
    int i = (bx - 3060) * 256 + t;
    const float* xs; int base, lg;
    if (i < 2097152)      { xs = x0; base = 0;       lg = 12; }
    else if (i < 2621440) { xs = x1; base = 2097152; lg = 10; }
    else if (i < 2752512) { xs = x2; base = 2621440; lg = 8;  }
    else if (i < 2785280) { xs = x3; base = 2752512; lg = 6;  }
    else return;
    int local = i - base;
    int HW = 1 << lg;
    int hw = local & (HW - 1);
    int plane = local >> lg;
    int tb = plane >> 7, cp = plane & 127;
    const float* s = xs + (size_t)(tb * 256 + cp * 2) * HW + hw;
    float f0 = s[0], f1 = s[HW];
    f16x2 h; h[0] = (_Float16)f0; h[1] = (_Float16)f1;
    xp[i] = __builtin_bit_cast(u32, h);
    return;
  }
  {
    int i = (bx - 13940) * 256 + t;
    if (i >= 2359296) return;
    int lv = i / 589824;
    const float* w = (lv == 0) ? w0 : (lv == 1) ? w1 : (lv == 2) ? w2 : w3;
    int local = i - lv * 589824;
    int o = local / 2304;
    int k = local - o * 2304;
    int g = k / 576;
    int r = k - g * 576;
    int p = r >> 6;
    int c = r & 63;
    float v = w[(size_t)(o * 256 + g * 64 + c) * 9 + p];
    __bf16 bv = (__bf16)v;
    A[i] = __builtin_bit_cast(u16, bv);
  }
}

// ---------------- correlation, L0/L1: hoisted staging + reg prefetch + dbuf LDS ----------------
// (r7-measured version: 68 us, VALUBusy 34%, conflicts 1.6M — LDS-pipe bound)
// k-split x4; block = 32 px x 8 k-groups; acc[10]; ONE barrier per channel chunk.
__global__ __launch_bounds__(256) void corr_big_kernel(const u32* __restrict__ xp, float* __restrict__ corr)
{
  __shared__ __align__(16) u32 x0w[6720];   // 2 x 3360 double buffer
  int t = threadIdx.x, bx = blockIdx.x;
  int stride, lgW, xpb, crb, b, tile, ks;
  if (bx < 1024) { stride = 2; lgW = 6; xpb = 0;       crb = 0;
                   int l = bx;        ks = l & 3; l >>= 2; b = l >> 7; tile = l & 127; }
  else           { stride = 1; lgW = 5; xpb = 2097152; crb = 2367488;
                   int l = bx - 1024; ks = l & 3; l >>= 2; b = l >> 5; tile = l & 31; }
  int W = 1 << lgW, HW = W * W;
  int E = stride * 8;
  int WW = 8 + 2 * E;                  // 40 (L0), 24 (L1)
  int tlg = lgW - 3;
  int ty0 = (tile >> tlg) * 4;
  int tx0 = (tile & ((1 << tlg) - 1)) * 8;
  int px = t & 31, kg = t >> 5;
  int tx = px & 7, ty = px >> 3;

  int kklo = ks * 10;
  int kkhi = (kklo + 10 < 37) ? kklo + 10 : 37;
  int klo = kklo * 8;
  int khi = kkhi * 8 - 1; if (khi > 288) khi = 288;
  int qylo = klo / 17, qyhi = khi / 17;
  int rowlo = stride * qylo;
  int nrows = 3 + stride * (qyhi - qylo) + 1;
  int stcount = nrows * WW * 4;        // max 2240 -> 9 slots
  int nslot = (stcount + 255) >> 8;

  int stabw[10];
#pragma unroll
  for (int j = 0; j < 10; ++j) {
    int k = (kklo + j) * 8 + kg;
    if (k > 288) k = 288;
    int qy = k / 17, qx = k - qy * 17;
    stabw[j] = ((ty + stride * qy - rowlo) * WW + tx + stride * qx) * 6;
  }
  float acc[10];
#pragma unroll
  for (int j = 0; j < 10; ++j) acc[j] = 0.f;

  // staging geometry hoist: per-slot u32 global word-offset + packed {write|laddr}
  int magic = (1 << 18) / WW + 1;
  u32 voff[9];
  u32 lvp[5] = {0u, 0u, 0u, 0u, 0u};
#pragma unroll
  for (int j = 0; j < 9; ++j) {
    u32 voj = 0, fl = 0;
    int idx = t + (j << 8);
    if (j < nslot && idx < stcount) {
      int s = idx >> 2, cw = idx & 3;
      int wy = (s * magic) >> 18;
      int wx = s - wy * WW;
      int gy = ty0 - E + rowlo + wy, gx = tx0 - E + wx;
      int la = s * 6 + cw;
      if ((u32)gy < (u32)W && (u32)gx < (u32)W) {
        voj = (u32)(cw * HW + (gy << lgW) + gx);
        fl = 0x8000u | (u32)la;
      } else {
        x0w[la] = 0; x0w[3360 + la] = 0;   // OOB sites chunk-invariant: zero once
      }
    }
    voff[j] = voj;
    lvp[j >> 1] |= fl << ((j & 1) * 16);
  }

  const u32* xp0 = xp + xpb + (size_t)b * 128 * HW;
  const u32* xp1 = xp + xpb + (size_t)(2 + b) * 128 * HW;
  int pxoff = ((ty0 + ty) << lgW) + (tx0 + tx);

  u32 pf[9];
  u32 xpf[4];
  auto issue = [&](int ch2) {
    u32 cb = (u32)(ch2 * 4) * (u32)HW;
#pragma unroll
    for (int j = 0; j < 9; ++j) if (j < nslot) pf[j] = xp0[cb + voff[j]];
#pragma unroll
    for (int i = 0; i < 4; ++i) xpf[i] = xp1[cb + (u32)(i * HW) + (u32)pxoff];
  };
  auto commit = [&](int bufb) {
#pragma unroll
    for (int j = 0; j < 9; ++j) {
      u32 w = lvp[j >> 1];
      u32 f = (j & 1) ? (w >> 16) : (w & 0xffffu);
      if (f & 0x8000u) x0w[bufb + (int)(f & 0x3fffu)] = pf[j];
    }
  };

  issue(0);
  for (int ch = 0; ch < 32; ++ch) {
    int bufb = (ch & 1) * 3360;
    commit(bufb);                     // waits only on pf(ch) (issued one chunk ago)
    __syncthreads();                  // LDS visible to all waves
    f16x2 xa0 = bch(xpf[0]), xa1 = bch(xpf[1]), xa2 = bch(xpf[2]), xa3 = bch(xpf[3]);
    if (ch < 31) issue(ch + 1);       // fly during compute
#pragma unroll
    for (int j = 0; j < 10; ++j) {
      int kk = kklo + j;
      int k = kk * 8 + kg;
      if (kk < kkhi && k < 289) {
        int a = bufb + stabw[j];
        uint2 v01 = *(const uint2*)(&x0w[a]);
        uint2 v23 = *(const uint2*)(&x0w[a + 2]);
        float s0 = acc[j];
        s0 = __builtin_amdgcn_fdot2(xa0, bch(v01.x), s0, false);
        s0 = __builtin_amdgcn_fdot2(xa1, bch(v01.y), s0, false);
        s0 = __builtin_amdgcn_fdot2(xa2, bch(v23.x), s0, false);
        s0 = __builtin_amdgcn_fdot2(xa3, bch(v23.y), s0, false);
        acc[j] = s0;
      }
    }
  }
  int gy = ty0 + ty, gx = tx0 + tx;
#pragma unroll
  for (int j = 0; j < 10; ++j) {
    int kk = kklo + j;
    int k = kk * 8 + kg;
    if (kk < kkhi && k < 289)
      corr[crb + (size_t)(b * 289 + k) * HW + (gy << lgW) + gx] = acc[j] * 0.00390625f;
  }
}

__global__ __launch_bounds__(256) void corr_small_kernel(const u32* __restrict__ xp, float* __restrict__ corr)
{
  int t = threadIdx.x;
  int gw = (blockIdx.x * 256 + t) >> 6;
  int lane = t & 63;
  int cs = lane >> 4, hwi = lane & 15;
  int obase = gw * 16;
  int K2, R, DISP, lgW, xpb, crb, rel;
  if (obase < 41472)      { K2 = 81; R = 9; DISP = 4; lgW = 4; xpb = 2621440; crb = 2959360; rel = obase; }
  else if (obase < 44672) { K2 = 25; R = 5; DISP = 2; lgW = 3; xpb = 2752512; crb = 3000832; rel = obase - 41472; }
  else return;
  int W = 1 << lgW, HW = W * W;
  int hw = (rel & (HW - 1)) + hwi;
  int rr = rel >> (2 * lgW);
  int k = rr % K2, b = rr / K2;
  int h = hw >> lgW, w = hw & (W - 1);
  int dy = k / R - DISP, dx = k % R - DISP;
  int h2 = h + dy, w2 = w + dx;
  float a = 0.f;
  if ((u32)h2 < (u32)W && (u32)w2 < (u32)W) {
    const u32* p1 = xp + xpb + (size_t)(2 + b) * 128 * HW + hw;
    const u32* p0 = xp + xpb + (size_t)b * 128 * HW + h2 * W + w2;
    int cp0 = cs * 32;
#pragma unroll 8
    for (int j = 0; j < 32; ++j) {
      int cp = cp0 + j;
      a = __builtin_amdgcn_fdot2(bch(p1[(size_t)cp * HW]), bch(p0[(size_t)cp * HW]), a, false);
    }
  }
  a += __shfl_xor(a, 16);
  a += __shfl_xor(a, 32);
  if (cs == 0)
    corr[crb + rel + hwi] = a * 0.00390625f;
}

// ---------------- offsets = w_off[72][K2] x corr[b][K2][HW], k-split x6, atomic combine ----
__global__ __launch_bounds__(256) void offset_kernel(
    const float* __restrict__ corr,
    const float* __restrict__ wo0, const float* __restrict__ wo1,
    const float* __restrict__ wo2, const float* __restrict__ wo3,
    float* __restrict__ offs)
{
  int t = threadIdx.x, bx = blockIdx.x;
  int kc = bx % 6;
  int unit = bx / 6;
  int og = unit & 3;
  int pb = unit >> 2;                 // 0..42

  int lgW, K2, crb, ofb, pbl;
  const float* wo;
  if (pb < 32)      { pbl = pb;      lgW = 6; K2 = 289; crb = 0;       ofb = 0;      wo = wo0; }
  else if (pb < 40) { pbl = pb - 32; lgW = 5; K2 = 289; crb = 2367488; ofb = 589824; wo = wo1; }
  else if (pb < 42) { pbl = pb - 40; lgW = 4; K2 = 81;  crb = 2959360; ofb = 737280; wo = wo2; }
  else              { pbl = 0;       lgW = 3; K2 = 25;  crb = 3000832; ofb = 774144; wo = wo3; }
  int HW = 1 << (2 * lgW);
  int pxg = pbl * 256 + t;
  if (lgW == 3 && t >= 128) return;   // L3 has only 128 px total
  int b = pxg >> (2 * lgW);
  int hw = pxg & (HW - 1);

  int kchunk = (K2 + 5) / 6;
  int klo = kc * kchunk;
  int khi = klo + kchunk; if (khi > K2) khi = K2;
  if (klo >= khi) return;

  const float* cr = corr + crb + (size_t)b * K2 * HW + hw;
  const float* wp = wo + (size_t)og * 18 * K2;   // block-uniform base
  float acc[18];
#pragma unroll
  for (int j = 0; j < 18; ++j) acc[j] = 0.f;
#pragma unroll 2
  for (int k = klo; k < khi; ++k) {
    float cv = cr[(size_t)k * HW];
#pragma unroll
    for (int j = 0; j < 18; ++j) acc[j] = fmaf(wp[(size_t)j * K2 + k], cv, acc[j]);
  }
  float* op = offs + ofb + ((size_t)b * 72 + og * 18) * HW + hw;
#pragma unroll
  for (int j = 0; j < 18; ++j) atomicAdd(&op[(size_t)j * HW], acc[j]);
}

__global__ __launch_bounds__(256) void repack_kernel(const u32* __restrict__ xp, u32* __restrict__ xq)
{
  __shared__ u32 lds[32 * 65];
  int t = threadIdx.x, bx = blockIdx.x;
  int local, lgW, xpb, xqb;
  if (bx < 512)      { local = bx;       lgW = 6; xpb = 0;       xqb = 0; }
  else if (bx < 640) { local = bx - 512; lgW = 5; xpb = 2097152; xqb = 1048576; }
  else if (bx < 672) { local = bx - 640; lgW = 4; xpb = 2621440; xqb = 1310720; }
  else               { local = bx - 672; lgW = 3; xpb = 2752512; xqb = 1376256; }
  int HW = 1 << (2 * lgW);
  int cpg_lg = 2 * lgW - 6;
  int hc = local & ((1 << cpg_lg) - 1);
  int g  = (local >> cpg_lg) & 3;
  int b  = local >> (cpg_lg + 2);
  int hw0 = hc * 64;
  int lane = t & 63, q = t >> 6;
  const u32* src = xp + xpb + (size_t)(2 + b) * 128 * HW + hw0 + lane;
#pragma unroll
  for (int j = 0; j < 8; ++j) {
    int p = q * 8 + j;
    lds[p * 65 + lane] = src[(size_t)(g * 32 + p) * HW];
  }
  __syncthreads();
  u32* dst = xq + xqb + ((size_t)((b * 4 + g) * HW + hw0)) * 32;
#pragma unroll
  for (int j = 0; j < 8; ++j) {
    int ow = j * 256 + t;
    int hwl = ow >> 5, w = ow & 31;
    dst[ow] = lds[w * 65 + hwl];
  }
}

// ---------------- bilinear sampler -> B[pix][2304] bf16 ----------------
__global__ __launch_bounds__(256) void sample_kernel(
    const u32* __restrict__ xq, const float* __restrict__ offs,
    u16* __restrict__ g0, u16* __restrict__ g1, u16* __restrict__ g2, u16* __restrict__ g3,
    u16* __restrict__ BB, int mode, int phase)
{
  int t = threadIdx.x, bx = blockIdx.x;
  int lvl, bsel, relblk;
  if (phase == 3) {
    if (bx < 2304)      { lvl = 0; bsel = 0; relblk = bx; }
    else if (bx < 4608) { lvl = 0; bsel = 1; relblk = bx - 2304; }
    else if (bx < 5760) { lvl = 1; bsel = 0; relblk = bx - 4608; }
    else if (bx < 6048) { lvl = 2; bsel = 0; relblk = bx - 5760; }
    else                { lvl = 3; bsel = 0; relblk = bx - 6048; }
  } else if (phase == 2) {
    if (bx < 1152)      { lvl = 1; bsel = 0; relblk = bx; }
    else if (bx < 1440) { lvl = 2; bsel = 0; relblk = bx - 1152; }
    else                { lvl = 3; bsel = 0; relblk = bx - 1440; }
  } else { lvl = 0; bsel = phase; relblk = bx; }

  int lgNPX = (lvl == 0) ? 12 : (lvl == 1) ? 11 : (lvl == 2) ? 9 : 7;
  int lgW   = (lvl == 0) ? 6  : (lvl == 1) ? 5  : (lvl == 2) ? 4 : 3;
  int xqb   = (lvl == 0) ? 0 : (lvl == 1) ? 1048576 : (lvl == 2) ? 1310720 : 1376256;
  int ofb   = (lvl == 0) ? 0 : (lvl == 1) ? 589824  : (lvl == 2) ? 737280  : 774144;
  int W = 1 << lgW, HW = W * W;

  int tid = relblk * 256 + t;
  int cq = tid & 3;
  int rest = tid >> 2;
  int px = rest & ((1 << lgNPX) - 1);
  int gp = rest >> lgNPX;

  int b, hw, cr, Rg;
  if (lvl == 0)      { b = bsel;     hw = px;        cr = px;       Rg = bsel * 4096 + px; }
  else if (lvl == 1) { b = px >> 10; hw = px & 1023; cr = px;       Rg = 8192 + px; }
  else if (lvl == 2) { b = px >> 8;  hw = px & 255;  cr = px;       Rg = 10240 + px; }
  else               { b = px >> 6;  hw = px & 63;   cr = 512 + px; Rg = 10752 + px; }

  u16* rowp;
  if (mode) rowp = BB + (size_t)Rg * 2304;
  else {
    u16* grp; int r;
    if (lvl >= 2) { grp = g2; r = cr; }
    else {
      int q = cr >> 10; r = cr & 1023;
      grp = (q == 0) ? g0 : (q == 1) ? g1 : (q == 2) ? g2 : g3;
    }
    rowp = grp + (size_t)r * 2304;
  }

  size_t ob = (size_t)ofb + ((size_t)b * 72 + gp * 2) * HW + hw;
  float ody = offs[ob], odx = offs[ob + HW];
  int g = gp / 9, p = gp - g * 9;
  int ky = p / 3, kx = p - ky * 3;
  int sh = hw >> lgW, sw = hw & (W - 1);
  float ys = (float)(sh + ky - 1) + ody;
  float xs = (float)(sw + kx - 1) + odx;
  float y0f = floorf(ys), x0f = floorf(xs);
  float wy = ys - y0f, wx = xs - x0f;
  int y0 = (int)y0f, x0 = (int)x0f, y1 = y0 + 1, x1 = x0 + 1;
  bool vy0 = (u32)y0 < (u32)W, vy1 = (u32)y1 < (u32)W;
  bool vx0 = (u32)x0 < (u32)W, vx1 = (u32)x1 < (u32)W;
  float w00 = (1.f - wy) * (1.f - wx), w01 = (1.f - wy) * wx;
  float w10 = wy * (1.f - wx), w11 = wy * wx;
  const u32* base = xq + xqb + ((size_t)(b * 4 + g) * HW) * 32 + cq * 8;
  const uint4 z = make_uint4(0, 0, 0, 0);
  uint4 a00 = z, c00 = z, a01 = z, c01 = z, a10 = z, c10 = z, a11 = z, c11 = z;
  if (vy0 && vx0) { const u32* p0 = base + (size_t)(y0 * W + x0) * 32; a00 = *(const uint4*)p0; c00 = *(const uint4*)(p0 + 4); }
  if (vy0 && vx1) { const u32* p0 = base + (size_t)(y0 * W + x1) * 32; a01 = *(const uint4*)p0; c01 = *(const uint4*)(p0 + 4); }
  if (vy1 && vx0) { const u32* p0 = base + (size_t)(y1 * W + x0) * 32; a10 = *(const uint4*)p0; c10 = *(const uint4*)(p0 + 4); }
  if (vy1 && vx1) { const u32* p0 = base + (size_t)(y1 * W + x1) * 32; a11 = *(const uint4*)p0; c11 = *(const uint4*)(p0 + 4); }
  bf16x8 r0, r1;
#pragma unroll
  for (int w = 0; w < 4; ++w) {
    f16x2 h00 = bch(((const u32*)&a00)[w]);
    f16x2 h01 = bch(((const u32*)&a01)[w]);
    f16x2 h10 = bch(((const u32*)&a10)[w]);
    f16x2 h11 = bch(((const u32*)&a11)[w]);
    float lo = w00 * (float)h00[0] + w01 * (float)h01[0] + w10 * (float)h10[0] + w11 * (float)h11[0];
    float hi = w00 * (float)h00[1] + w01 * (float)h01[1] + w10 * (float)h10[1] + w11 * (float)h11[1];
    r0[2 * w] = (__bf16)lo; r0[2 * w + 1] = (__bf16)hi;
  }
#pragma unroll
  for (int w = 0; w < 4; ++w) {
    f16x2 h00 = bch(((const u32*)&c00)[w]);
    f16x2 h01 = bch(((const u32*)&c01)[w]);
    f16x2 h10 = bch(((const u32*)&c10)[w]);
    f16x2 h11 = bch(((const u32*)&c11)[w]);
    float lo = w00 * (float)h00[0] + w01 * (float)h01[0] + w10 * (float)h10[0] + w11 * (float)h11[0];
    float hi = w00 * (float)h00[1] + w01 * (float)h01[1] + w10 * (float)h10[1] + w11 * (float)h11[1];
    r1[2 * w] = (__bf16)lo; r1[2 * w + 1] = (__bf16)hi;
  }
  u16* dst = rowp + gp * 64 + cq * 16;
  *(bf16x8*)dst = r0;
  *(bf16x8*)(dst + 8) = r1;
}

// ---------------- clean GEMM: C[256][pix] = A[256][2304] x B[pix][2304]^T + ReLU ----------------
__global__ __launch_bounds__(256) void gemm2_kernel(
    const u16* __restrict__ A,
    const u16* __restrict__ g0, const u16* __restrict__ g1,
    const u16* __restrict__ g2, const u16* __restrict__ g3,
    const u16* __restrict__ BB, int mode, int phase,
    float* __restrict__ out)
{
  __shared__ __align__(16) u16 Al[64 * 72];
  __shared__ __align__(16) u16 Bl[32 * 72];
  int t = threadIdx.x, bx = blockIdx.x;

  int lvl, bsel, local;
  if (phase == 3) {
    if (bx < 512)       { lvl = 0; bsel = 0; local = bx; }
    else if (bx < 1024) { lvl = 0; bsel = 1; local = bx - 512; }
    else {
      int r = bx - 1024;
      if (r < 256)      { lvl = 1; local = r; bsel = 0; }
      else if (r < 320) { lvl = 2; local = r - 256; bsel = 0; }
      else              { lvl = 3; local = r - 320; bsel = 0; }
    }
  } else if (phase == 2) {
    if (bx < 256)      { lvl = 1; local = bx; bsel = 0; }
    else if (bx < 320) { lvl = 2; local = bx - 256; bsel = 0; }
    else               { lvl = 3; local = bx - 320; bsel = 0; }
  } else { lvl = 0; bsel = phase; local = bx; }

  int mt = local & 3, nt = local >> 2;
  int px0 = nt * 32;
  int lgW, Ab, outb, b, hw0, cr0, Rg;
  if (lvl == 0)      { lgW = 6; Ab = 0;       outb = 2097152; b = bsel;      hw0 = px0;        cr0 = px0;       Rg = bsel * 4096 + px0; }
  else if (lvl == 1) { lgW = 5; Ab = 589824;  outb = 4718592; b = px0 >> 10; hw0 = px0 & 1023; cr0 = px0;       Rg = 8192 + px0; }
  else if (lvl == 2) { lgW = 4; Ab = 1179648; outb = 5373952; b = px0 >> 8;  hw0 = px0 & 255;  cr0 = px0;       Rg = 10240 + px0; }
  else               { lgW = 3; Ab = 1769472; outb = 5537792; b = px0 >> 6;  hw0 = px0 & 63;   cr0 = 512 + px0; Rg = 10752 + px0; }
  int HW = 1 << (2 * lgW);

  const u16* Bbase;
  if (mode) Bbase = BB + (size_t)Rg * 2304;
  else {
    const u16* grp; int r;
    if (lvl >= 2) { grp = g2; r = cr0; }
    else {
      int q = cr0 >> 10; r = cr0 & 1023;
      grp = (q == 0) ? g0 : (q == 1) ? g1 : (q == 2) ? g2 : g3;
    }
    Bbase = grp + (size_t)r * 2304;
  }

  int o0 = mt * 64;
  int l = t & 63, wv = t >> 6;
  int lr = l & 15, lk = l >> 4;
  int wvr = wv >> 1, wvc = wv & 1;

  int arow = t >> 2, ac4 = t & 3;
  int brow = t >> 3, bc8 = t & 7;
  const u16* Asrc = A + Ab + (size_t)(o0 + arow) * 2304 + ac4 * 16;
  const u16* Bsrc = Bbase + (size_t)brow * 2304 + bc8 * 8;

  f32x4 acc0 = {0, 0, 0, 0}, acc1 = {0, 0, 0, 0};
  uint4 ar0, ar1, br;
  auto issue = [&](int k0) {
    const uint4* as = (const uint4*)(Asrc + k0);
    ar0 = as[0]; ar1 = as[1];
    br = *(const uint4*)(Bsrc + k0);
  };
  auto commit = [&]() {
    *(uint4*)(&Al[arow * 72 + ac4 * 16]) = ar0;
    *(uint4*)(&Al[arow * 72 + ac4 * 16 + 8]) = ar1;
    *(uint4*)(&Bl[brow * 72 + bc8 * 8]) = br;
  };
  issue(0); commit();
  __syncthreads();
#pragma unroll 1
  for (int kt = 0; kt < 36; ++kt) {
    if (kt < 35) issue((kt + 1) * 64);
#pragma unroll
    for (int kk = 0; kk < 2; ++kk) {
      bf16x8 b0 = *(const bf16x8*)(&Bl[(wvc * 16 + lr) * 72 + kk * 32 + lk * 8]);
      bf16x8 a0 = *(const bf16x8*)(&Al[(wvr * 32 + lr) * 72 + kk * 32 + lk * 8]);
      bf16x8 a1 = *(const bf16x8*)(&Al[(wvr * 32 + 16 + lr) * 72 + kk * 32 + lk * 8]);
      acc0 = __builtin_amdgcn_mfma_f32_16x16x32_bf16(a0, b0, acc0, 0, 0, 0);
      acc1 = __builtin_amdgcn_mfma_f32_16x16x32_bf16(a1, b0, acc1, 0, 0, 0);
    }
    __syncthreads();
    if (kt < 35) { commit(); __syncthreads(); }
  }
  float* op = out + outb + (size_t)b * 256 * HW;
#pragma unroll
  for (int j = 0; j < 4; ++j) {
    int orow = o0 + wvr * 32 + lk * 4 + j;
    int col = hw0 + wvc * 16 + lr;
    op[(size_t)orow * HW + col]        = fmaxf(acc0[j], 0.f);
    op[(size_t)(orow + 16) * HW + col] = fmaxf(acc1[j], 0.f);
  }
}

extern "C" void kernel_launch(void* const* d_in, const int* in_sizes, int n_in,
                              void* d_out, int out_size, void* d_ws, size_t ws_size,
                              hipStream_t stream) {
  const float* x[4];
  const float* woff[4];
  const float* wad[4];
  for (int l = 0; l < 4; ++l) {
    x[l]    = (const float*)d_in[l];
    woff[l] = (const float*)d_in[4 + 2 * l];
    wad[l]  = (const float*)d_in[5 + 2 * l];
  }
  float* out = (float*)d_out;
  char* ws = (char*)d_ws;
  u32*   xp   = (u32*)(ws);
  u16*   A    = (u16*)(ws + 11141120);
  float* corr = (float*)(ws + 15859712);
  u32*   xq   = (u32*)(ws + 15859712);
  float* offs = (float*)(ws + 27875840);
  u16* g0 = (u16*)(ws + 0);
  u16* g1 = (u16*)(ws + 4718592);
  u16* g2 = (u16*)(ws + 21430272);
  u16* g3 = (u16*)d_out;
  u16* BB = (u16*)(ws + 31009280);
  int big = (ws_size >= (size_t)81144320) ? 1 : 0;

  prep_kernel<<<23156, 256, 0, stream>>>(x[0], x[1], x[2], x[3],
                                         wad[0], wad[1], wad[2], wad[3], xp, A, offs);
  corr_big_kernel<<<1280, 256, 0, stream>>>(xp, corr);
  corr_small_kernel<<<698, 256, 0, stream>>>(xp, corr);
  offset_kernel<<<1032, 256, 0, stream>>>(corr, woff[0], woff[1], woff[2], woff[3], offs);
  repack_kernel<<<680, 256, 0, stream>>>(xp, xq);

  if (big) {
    sample_kernel<<<6120, 256, 0, stream>>>(xq, offs, g0, g1, g2, g3, BB, 1, 3);
    gemm2_kernel<<<1360, 256, 0, stream>>>(A, g0, g1, g2, g3, BB, 1, 3, out);
  } else {
    sample_kernel<<<2304, 256, 0, stream>>>(xq, offs, g0, g1, g2, g3, BB, 0, 0);
    gemm2_kernel<<<512, 256, 0, stream>>>(A, g0, g1, g2, g3, BB, 0, 0, out);
    sample_kernel<<<2304, 256, 0, stream>>>(xq, offs, g0, g1, g2, g3, BB, 0, 1);
    gemm2_kernel<<<512, 256, 0, stream>>>(A, g0, g1, g2, g3, BB, 0, 1, out);
    sample_kernel<<<1512, 256, 0, stream>>>(xq, offs, g0, g1, g2, g3, BB, 0, 2);
    gemm2_kernel<<<336, 256, 0, stream>>>(A, g0, g1, g2, g3, BB, 0, 2, out);
  }

  hipMemcpyAsync(out + 0,       x[0], (size_t)2097152 * 4, hipMemcpyDeviceToDevice, stream);
  hipMemcpyAsync(out + 4194304, x[1], (size_t)524288 * 4,  hipMemcpyDeviceToDevice, stream);
  hipMemcpyAsync(out + 5242880, x[2], (size_t)131072 * 4,  hipMemcpyDeviceToDevice, stream);
  hipMemcpyAsync(out + 5505024, x[3], (size_t)32768 * 4,   hipMemcpyDeviceToDevice, stream);
}